// Round 3
// baseline (151.046 us; speedup 1.0000x reference)
//
#include <hip/hip_runtime.h>
#include <hip/hip_bf16.h>

using bf16x8 = __attribute__((ext_vector_type(8))) short;
using f32x4  = __attribute__((ext_vector_type(4))) float;

constexpr int CH  = 64;
constexpr int HW  = 11;
constexpr int NP  = 121;
constexpr int PPW = 14;    // padded pos row width
constexpr int NPP = 182;   // padded positions (13x14)
constexpr int ICP = 72;    // padded ic stride (bf16)
constexpr int NOCP = 112;  // padded oc (100 -> 112)
constexpr int NO  = NOCP * 64;   // 7168 padded o-rows
constexpr int NT  = NO / 16;     // 448 MFMA tiles
constexpr float EPS = 1e-5f;

// ---- prep: bake BN-scaled gw into MFMA-A-fragment order + beta ----
__global__ __launch_bounds__(256) void prep_kernel(
    const float* __restrict__ gw, const float* __restrict__ gb,
    const float* __restrict__ bng, const float* __restrict__ bnb,
    const float* __restrict__ bnm, const float* __restrict__ bnv,
    unsigned short* __restrict__ Aprep, float* __restrict__ Beta)
{
    int o = blockIdx.x * 256 + threadIdx.x;   // padded o = oc*64+ic, oc<112
    if (o >= NO) return;
    float inv = 0.f, beta = 0.f;
    if (o < 6400) {
        inv  = bng[o] * rsqrtf(bnv[o] + EPS);
        beta = (gb[o] - bnm[o]) * inv + bnb[o];
    }
    Beta[o] = beta;
    int tile = o >> 4, lrow = o & 15;
    #pragma unroll
    for (int jg = 0; jg < 4; ++jg) {
        bf16x8 f;
        #pragma unroll
        for (int r = 0; r < 8; ++r) {
            int k = jg * 8 + r;
            float v = (o < 6400 && k < 18) ? gw[(size_t)o * 18 + k] * inv : 0.f;
            __hip_bfloat16 h = __float2bfloat16(v);
            f[r] = *(short*)&h;
        }
        // A-frag layout: lane holds A[row=lane&15][k=(lane>>4)*8+r]
        ((bf16x8*)Aprep)[tile * 64 + jg * 16 + lrow] = f;
    }
}

// ---- main fused kernel: one block per sample ----
__global__ __launch_bounds__(256, 2) void hsi_main(
    const float* __restrict__ x_in,
    const unsigned short* __restrict__ Aprep,
    const float* __restrict__ Beta,
    float* __restrict__ out)
{
    __shared__ alignas(16) unsigned short xsT[NPP][ICP];   // 26208 B
    __shared__ alignas(16) unsigned short Wc[9][32][ICP];  // 41472 B
    __shared__ alignas(16) unsigned short BgenT[16][40];   // 1280 B
    __shared__ float xh[2][128];                           // pooled avg|max
    __shared__ float xhp[2][2][128];                       // pooling partials

    const int b = blockIdx.x, t = threadIdx.x;
    const int lane = t & 63, wave = t >> 6;
    const int lrow = lane & 15, jg = lane >> 4;
    const float* xb = x_in + (size_t)b * (CH * NP);

    for (int i = t; i < NPP * ICP / 2; i += 256) ((unsigned int*)xsT)[i] = 0u;
    if (t < 320) ((unsigned int*)BgenT)[t] = 0u;
    __syncthreads();

    // ---- phase 1: coalesced fp32 load, exact pool partials, bf16 transpose ----
    {
        int p = (wave & 1) * 64 + lane;   // waves {0,2}: p=0..63, {1,3}: 64..127
        int ich = wave >> 1;              // ic half
        if (p < NP) {
            int pp = (p / HW + 1) * PPW + (p % HW + 1);
            float s = 0.f, m = -INFINITY;
            const float* xc = xb + (ich * 32) * NP + p;
            #pragma unroll 8
            for (int q = 0; q < 32; ++q) {
                float v = xc[q * NP];     // lanes: consecutive p -> coalesced
                s += v; m = fmaxf(m, v);
                __hip_bfloat16 h = __float2bfloat16(v);
                xsT[pp][ich * 32 + q] = *(unsigned short*)&h;
            }
            xhp[ich][0][p] = s;
            xhp[ich][1][p] = m;
        }
    }
    __syncthreads();
    if (t < NP) {
        xh[0][t] = (xhp[0][0][t] + xhp[1][0][t]) * (1.f / 64.f);
        xh[1][t] = fmaxf(xhp[0][1][t], xhp[1][1][t]);
    }
    __syncthreads();
    // gen-GEMM B operand: BgenT[tap][k], k = ci*9 + u*3 + v (gw flat order)
    if (t < 162) {
        int tap = t / 18, k = t - tap * 18;
        int ci = k / 9, o9 = k - ci * 9, u = o9 / 3, v = o9 - u * 3;
        int kh = tap / 3, kw = tap - kh * 3;
        float val = xh[ci][(4 * kh + u) * HW + (4 * kw + v)];
        __hip_bfloat16 h = __float2bfloat16(val);
        BgenT[tap][k] = *(unsigned short*)&h;
    }
    __syncthreads();

    // hoisted gen B-fragment (constant for whole kernel)
    bf16x8 Bgen = *(const bf16x8*)&BgenT[lrow][jg * 8];

    // main-GEMM B positional bases (wave owns 32 positions = 2 N-tiles)
    int ppb[2], pst[2];
    #pragma unroll
    for (int nt = 0; nt < 2; ++nt) {
        int p = wave * 32 + nt * 16 + lrow;
        pst[nt] = p;
        int pc = p > 120 ? 120 : p;
        ppb[nt] = (pc / HW) * PPW + (pc % HW);
    }

    for (int c = 0; c < 4; ++c) {
        // ---- gen phase: 32 MFMAs/wave, A from global (coalesced 16B/lane) ----
        #pragma unroll 4
        for (int it = 0; it < 32; ++it) {
            int tileG = c * 128 + wave * 32 + it;
            bf16x8 A = *(const bf16x8*)(Aprep + (size_t)(tileG * 64 + lane) * 8);
            f32x4 acc{};
            acc = __builtin_amdgcn_mfma_f32_16x16x32_bf16(A, Bgen, acc, 0, 0, 0);
            int obase = tileG * 16 + jg * 4;
            float4 bet = *(const float4*)(Beta + obase);
            if (lrow < 9) {   // col = tap
                float v0 = fmaxf(acc[0] + bet.x, 0.f);
                float v1 = fmaxf(acc[1] + bet.y, 0.f);
                float v2 = fmaxf(acc[2] + bet.z, 0.f);
                float v3 = fmaxf(acc[3] + bet.w, 0.f);
                __hip_bfloat16 h0 = __float2bfloat16(v0), h1 = __float2bfloat16(v1);
                __hip_bfloat16 h2 = __float2bfloat16(v2), h3 = __float2bfloat16(v3);
                unsigned int lo = (unsigned int)*(unsigned short*)&h0 |
                                  ((unsigned int)*(unsigned short*)&h1 << 16);
                unsigned int hi = (unsigned int)*(unsigned short*)&h2 |
                                  ((unsigned int)*(unsigned short*)&h3 << 16);
                int oloc = (tileG & 127) * 16 + jg * 4;   // o within chunk
                int icq = (oloc & 63) ^ ((lrow & 7) << 3); // tap-XOR swizzle (8-elem granule)
                uint2 pk; pk.x = lo; pk.y = hi;
                *(uint2*)&Wc[lrow][oloc >> 6][icq] = pk;
            }
        }
        __syncthreads();

        // ---- main MFMA: 2 M-tiles x 2 N-tiles per wave ----
        f32x4 a00{}, a01{}, a10{}, a11{};
        #pragma unroll
        for (int tap = 0; tap < 9; ++tap) {
            int tapoff = (tap / 3) * PPW + (tap % 3);
            int sw = (tap & 7) << 3;
            #pragma unroll
            for (int k0 = 0; k0 < 64; k0 += 32) {
                int kk = k0 + jg * 8;
                int kks = kk ^ sw;   // undo write swizzle (16B-aligned granule)
                bf16x8 A0 = *(const bf16x8*)&Wc[tap][lrow][kks];
                bf16x8 A1 = *(const bf16x8*)&Wc[tap][16 + lrow][kks];
                bf16x8 B0 = *(const bf16x8*)&xsT[ppb[0] + tapoff][kk];
                bf16x8 B1 = *(const bf16x8*)&xsT[ppb[1] + tapoff][kk];
                a00 = __builtin_amdgcn_mfma_f32_16x16x32_bf16(A0, B0, a00, 0, 0, 0);
                a01 = __builtin_amdgcn_mfma_f32_16x16x32_bf16(A0, B1, a01, 0, 0, 0);
                a10 = __builtin_amdgcn_mfma_f32_16x16x32_bf16(A1, B0, a10, 0, 0, 0);
                a11 = __builtin_amdgcn_mfma_f32_16x16x32_bf16(A1, B1, a11, 0, 0, 0);
            }
        }

        // ---- store (C/D layout: col=lane&15, row=(lane>>4)*4+reg) ----
        #pragma unroll
        for (int mt = 0; mt < 2; ++mt) {
            #pragma unroll
            for (int nt = 0; nt < 2; ++nt) {
                f32x4 vv = (mt == 0) ? (nt == 0 ? a00 : a01)
                                     : (nt == 0 ? a10 : a11);
                int p = pst[nt];
                if (p < NP) {
                    #pragma unroll
                    for (int ri = 0; ri < 4; ++ri) {
                        int oc = c * 32 + mt * 16 + jg * 4 + ri;
                        if (oc < 100)
                            out[((size_t)b * 100 + oc) * NP + p] = vv[ri];
                    }
                }
            }
        }
        __syncthreads();
    }
}

extern "C" void kernel_launch(void* const* d_in, const int* in_sizes, int n_in,
                              void* d_out, int out_size, void* d_ws, size_t ws_size,
                              hipStream_t stream) {
    const float* x  = (const float*)d_in[0];
    const float* gw = (const float*)d_in[1];
    const float* gb = (const float*)d_in[2];
    const float* bg = (const float*)d_in[3];
    const float* bb = (const float*)d_in[4];
    const float* bm = (const float*)d_in[5];
    const float* bv = (const float*)d_in[6];
    float* out = (float*)d_out;

    // ws layout: Aprep (448*64*8 bf16 = 458752 B) | Beta (7168 f32 = 28672 B)
    unsigned short* Aprep = (unsigned short*)d_ws;
    float* Beta = (float*)((char*)d_ws + (size_t)NT * 64 * 8 * sizeof(unsigned short));

    prep_kernel<<<NO / 256, 256, 0, stream>>>(gw, gb, bg, bb, bm, bv, Aprep, Beta);

    const int nb = in_sizes[0] / (CH * NP);  // 1024
    hsi_main<<<nb, 256, 0, stream>>>(x, Aprep, Beta, out);
}